// Round 3
// baseline (228.876 us; speedup 1.0000x reference)
//
#include <hip/hip_runtime.h>
#include <hip/hip_bf16.h>

typedef __attribute__((ext_vector_type(4))) float f32x4;
typedef __attribute__((ext_vector_type(8))) short bf16x8;

__device__ inline short f2b(float f) {
    union { float f; unsigned u; } v; v.f = f;
    unsigned r = v.u + 0x7FFF + ((v.u >> 16) & 1);  // RNE
    return (short)(r >> 16);
}
__device__ inline unsigned pack2(float lo, float hi) {
    return (unsigned)(unsigned short)f2b(lo) | ((unsigned)(unsigned short)f2b(hi) << 16);
}

// ---------------- Prologue: B (fp32, row-major) -> Btr (bf16, [seq][head][col][k]) ----------------
__global__ __launch_bounds__(256) void transposeB(const float* __restrict__ b,
                                                  unsigned short* __restrict__ bt) {
    const int cumtb[9] = {0,128,384,896,1280,1472,1792,2016,2176};
    const int slen[8]  = {512,1024,2048,1536,768,1280,896,640};
    const int toff[8]  = {0,512,1536,3584,5120,5888,7168,8064};
    __shared__ unsigned short T[64][72];  // [col][k] for one 64-token tile

    int bid = blockIdx.x;
    int i = 0;
    #pragma unroll
    for (int t = 0; t < 7; ++t) if (bid >= cumtb[t + 1]) i = t + 1;
    int rem  = bid - cumtb[i];
    int s    = slen[i];
    int nkt  = s >> 6;
    int head = rem / nkt;
    int t0   = (rem - head * nkt) << 6;

    int tid = threadIdx.x;
    int row = tid >> 2, cg = tid & 3;  // 4 threads cover one token's 64 cols
    const float* src = b + (long)(toff[i] + t0 + row) * 1024 + head * 64 + cg * 16;
    #pragma unroll
    for (int e4 = 0; e4 < 4; ++e4) {
        f32x4 v = *(const f32x4*)(src + e4 * 4);
        #pragma unroll
        for (int e = 0; e < 4; ++e)
            T[cg * 16 + e4 * 4 + e][row] = (unsigned short)f2b(v[e]);
    }
    __syncthreads();
    // Write phase: each thread owns 16 k-elements of one column (BOTH 8-short halves!)
    int col = tid >> 2, kq = tid & 3;
    unsigned short* dst = bt + (long)toff[i] * 1024 + (long)head * 64 * s
                             + (long)col * s + t0 + kq * 16;
    *(bf16x8*)dst       = *(const bf16x8*)&T[col][kq * 16];
    *(bf16x8*)(dst + 8) = *(const bf16x8*)&T[col][kq * 16 + 8];
}

// ---------------- Main: barrier-free, LDS-free ragged bmm2 ----------------
__global__ __launch_bounds__(256) void bmm2_main(const float* __restrict__ a,
                                                 const unsigned short* __restrict__ bt,
                                                 float* __restrict__ out) {
    // Longest-seq-first block order (kills the load-imbalance tail).
    const int  cumblk[9] = {0,256,448,608,736,848,944,1024,1088};
    const int  slen[8]   = {2048,1536,1280,1024,896,768,640,512};
    const long aoff[8]   = {20971520,88080384,135266304,4194304,161480704,125829120,174325760,0};
    const int  toff[8]   = {1536,3584,5888,512,7168,5120,8064,0};

    int bid = blockIdx.x;
    int i = 0;
    #pragma unroll
    for (int t = 0; t < 7; ++t) if (bid >= cumblk[t + 1]) i = t + 1;
    int rem  = bid - cumblk[i];
    int s    = slen[i];
    int nmb  = s >> 7;
    int head = rem / nmb;
    int mb   = rem - head * nmb;

    const float* A = a + aoff[i] + (long)head * s * s + (long)mb * 128 * s;
    const unsigned short* Bt = bt + (long)toff[i] * 1024 + (long)head * 64 * s;
    float* Cp = out + (long)(toff[i] + mb * 128) * 1024 + head * 64;

    int tid = threadIdx.x, lane = tid & 63, wave = tid >> 6;
    int lrow = lane & 15, lgrp = lane >> 4;

    const float* ar0 = A + (long)(wave * 32 + lrow) * s + lgrp * 8;
    const float* ar1 = ar0 + (long)16 * s;
    const unsigned short* bp = Bt + (long)lrow * s + lgrp * 8;

    f32x4 acc[2][4] = {};

    for (int k0 = 0; k0 < s; k0 += 64) {
        // A: the 723 MB stream, straight global->VGPR (128 B contiguous per row per wave)
        f32x4 a00 = *(const f32x4*)(ar0 + k0);
        f32x4 a01 = *(const f32x4*)(ar0 + k0 + 4);
        f32x4 a10 = *(const f32x4*)(ar1 + k0);
        f32x4 a11 = *(const f32x4*)(ar1 + k0 + 4);
        f32x4 a02 = *(const f32x4*)(ar0 + k0 + 32);
        f32x4 a03 = *(const f32x4*)(ar0 + k0 + 36);
        f32x4 a12 = *(const f32x4*)(ar1 + k0 + 32);
        f32x4 a13 = *(const f32x4*)(ar1 + k0 + 36);

        // B: bf16 fragments, already in MFMA lane order (L1/L2-resident)
        bf16x8 bf0[4], bf1[4];
        #pragma unroll
        for (int nt = 0; nt < 4; ++nt) {
            bf0[nt] = *(const bf16x8*)(bp + (long)nt * 16 * s + k0);
            bf1[nt] = *(const bf16x8*)(bp + (long)nt * 16 * s + k0 + 32);
        }

        bf16x8 af0, af1, af2, af3;
        #pragma unroll
        for (int e = 0; e < 4; ++e) {
            af0[e] = f2b(a00[e]); af0[e + 4] = f2b(a01[e]);
            af1[e] = f2b(a10[e]); af1[e + 4] = f2b(a11[e]);
            af2[e] = f2b(a02[e]); af2[e + 4] = f2b(a03[e]);
            af3[e] = f2b(a12[e]); af3[e + 4] = f2b(a13[e]);
        }

        #pragma unroll
        for (int nt = 0; nt < 4; ++nt) {
            acc[0][nt] = __builtin_amdgcn_mfma_f32_16x16x32_bf16(af0, bf0[nt], acc[0][nt], 0, 0, 0);
            acc[1][nt] = __builtin_amdgcn_mfma_f32_16x16x32_bf16(af1, bf0[nt], acc[1][nt], 0, 0, 0);
        }
        #pragma unroll
        for (int nt = 0; nt < 4; ++nt) {
            acc[0][nt] = __builtin_amdgcn_mfma_f32_16x16x32_bf16(af2, bf1[nt], acc[0][nt], 0, 0, 0);
            acc[1][nt] = __builtin_amdgcn_mfma_f32_16x16x32_bf16(af3, bf1[nt], acc[1][nt], 0, 0, 0);
        }
    }

    // Epilogue: C/D layout col=lane&15, row=4*(lane>>4)+reg (verified round 1)
    #pragma unroll
    for (int mt = 0; mt < 2; ++mt)
        #pragma unroll
        for (int nt = 0; nt < 4; ++nt)
            #pragma unroll
            for (int r = 0; r < 4; ++r) {
                int q = wave * 32 + mt * 16 + lgrp * 4 + r;
                Cp[(long)q * 1024 + nt * 16 + lrow] = acc[mt][nt][r];
            }
}

// ---------------- Fallback (round-1 kernel) if ws too small ----------------
#define LDB 40
__global__ __launch_bounds__(256) void bmm2_kernel_lds(const float* __restrict__ a,
                                                       const float* __restrict__ b,
                                                       float* __restrict__ out) {
    const int  cumblk[9] = {0,64,192,448,640,736,896,1008,1088};
    const int  slen[8]   = {512,1024,2048,1536,768,1280,896,640};
    const long aoff[8]   = {0,4194304,20971520,88080384,125829120,135266304,161480704,174325760};
    const int  toff[8]   = {0,512,1536,3584,5120,5888,7168,8064};
    __shared__ unsigned short Bt[64 * LDB];

    int bid = blockIdx.x;
    int i = 0;
    #pragma unroll
    for (int t = 0; t < 7; ++t) if (bid >= cumblk[t + 1]) i = t + 1;
    int rem = bid - cumblk[i];
    int s = slen[i];
    int nmb = s >> 7;
    int head = rem / nmb;
    int mb = rem - head * nmb;

    const float* A  = a + aoff[i] + (long)head * s * s + (long)mb * 128 * s;
    const float* Bp = b + (long)toff[i] * 1024 + head * 64;
    float*       Cp = out + (long)(toff[i] + mb * 128) * 1024 + head * 64;

    int tid = threadIdx.x, lane = tid & 63, wave = tid >> 6;
    int lrow = lane & 15, lgrp = lane >> 4;
    f32x4 acc[2][4] = {};
    int k2 = tid >> 4;
    int j0 = (tid & 15) * 4;
    const float* arow0 = A + (long)(wave * 32 + lrow) * s + lgrp * 8;
    const float* arow1 = arow0 + (long)16 * s;

    for (int k0 = 0; k0 < s; k0 += 32) {
        f32x4 a00 = *(const f32x4*)(arow0 + k0);
        f32x4 a01 = *(const f32x4*)(arow0 + k0 + 4);
        f32x4 a10 = *(const f32x4*)(arow1 + k0);
        f32x4 a11 = *(const f32x4*)(arow1 + k0 + 4);
        const float* bpp = Bp + (long)(k0 + 2 * k2) * 1024 + j0;
        f32x4 b0 = *(const f32x4*)bpp;
        f32x4 b1 = *(const f32x4*)(bpp + 1024);
        __syncthreads();
        #pragma unroll
        for (int e = 0; e < 4; ++e)
            *(unsigned*)&Bt[(j0 + e) * LDB + 2 * k2] = pack2(b0[e], b1[e]);
        __syncthreads();
        bf16x8 bf[4];
        #pragma unroll
        for (int nt = 0; nt < 4; ++nt)
            bf[nt] = *(const bf16x8*)&Bt[(nt * 16 + lrow) * LDB + lgrp * 8];
        bf16x8 af0, af1;
        #pragma unroll
        for (int e = 0; e < 4; ++e) {
            af0[e] = f2b(a00[e]); af0[e + 4] = f2b(a01[e]);
            af1[e] = f2b(a10[e]); af1[e + 4] = f2b(a11[e]);
        }
        #pragma unroll
        for (int nt = 0; nt < 4; ++nt) {
            acc[0][nt] = __builtin_amdgcn_mfma_f32_16x16x32_bf16(af0, bf[nt], acc[0][nt], 0, 0, 0);
            acc[1][nt] = __builtin_amdgcn_mfma_f32_16x16x32_bf16(af1, bf[nt], acc[1][nt], 0, 0, 0);
        }
    }
    #pragma unroll
    for (int mt = 0; mt < 2; ++mt)
        #pragma unroll
        for (int nt = 0; nt < 4; ++nt)
            #pragma unroll
            for (int r = 0; r < 4; ++r) {
                int q = wave * 32 + mt * 16 + lgrp * 4 + r;
                Cp[(long)q * 1024 + nt * 16 + lrow] = acc[mt][nt][r];
            }
}

extern "C" void kernel_launch(void* const* d_in, const int* in_sizes, int n_in,
                              void* d_out, int out_size, void* d_ws, size_t ws_size,
                              hipStream_t stream) {
    const float* a = (const float*)d_in[0];
    const float* b = (const float*)d_in[1];
    float* out = (float*)d_out;
    const size_t BT_BYTES = 8704UL * 1024UL * 2UL;  // 17.8 MB bf16 transposed B
    if (ws_size >= BT_BYTES) {
        transposeB<<<2176, 256, 0, stream>>>(b, (unsigned short*)d_ws);
        bmm2_main<<<1088, 256, 0, stream>>>(a, (const unsigned short*)d_ws, out);
    } else {
        bmm2_kernel_lds<<<1088, 256, 0, stream>>>(a, b, out);
    }
}

// Round 4
// 200.844 us; speedup vs baseline: 1.1396x; 1.1396x over previous
//
#include <hip/hip_runtime.h>
#include <hip/hip_bf16.h>

typedef __attribute__((ext_vector_type(4))) float f32x4;
typedef __attribute__((ext_vector_type(8))) short bf16x8;

__device__ inline short f2b(float f) {
    union { float f; unsigned u; } v; v.f = f;
    unsigned r = v.u + 0x7FFF + ((v.u >> 16) & 1);  // RNE
    return (short)(r >> 16);
}

__device__ __forceinline__ unsigned cvt2(float lo, float hi) {
    float2 t; t.x = lo; t.y = hi;
    __hip_bfloat162 h = __float22bfloat162_rn(t);   // -> v_cvt_pk_bf16_f32
    union { __hip_bfloat162 h; unsigned u; } c; c.h = h; return c.u;
}
__device__ __forceinline__ bf16x8 cvt8(f32x4 lo, f32x4 hi) {
    union { bf16x8 v; unsigned u[4]; } r;
    r.u[0] = cvt2(lo[0], lo[1]); r.u[1] = cvt2(lo[2], lo[3]);
    r.u[2] = cvt2(hi[0], hi[1]); r.u[3] = cvt2(hi[2], hi[3]);
    return r.v;
}

#define GLDS(G, L) __builtin_amdgcn_global_load_lds( \
    (const __attribute__((address_space(1))) void*)(G), \
    (__attribute__((address_space(3))) void*)(L), 16, 0, 0)

// ---- Prologue: B (fp32 row-major) -> Bt (bf16, [seq][head][col j][k], chunk-swizzled) ----
// Within each (j, 64k-window): 16B chunk at position p holds original chunk p ^ (j&7).
__global__ __launch_bounds__(256) void transposeB(const float* __restrict__ b,
                                                  unsigned short* __restrict__ bt) {
    const int cumtb[9] = {0,128,384,896,1280,1472,1792,2016,2176};
    const int slen[8]  = {512,1024,2048,1536,768,1280,896,640};
    const int toff[8]  = {0,512,1536,3584,5120,5888,7168,8064};
    __shared__ unsigned short T[64][72];

    int bid = blockIdx.x;
    int i = 0;
    #pragma unroll
    for (int t = 0; t < 7; ++t) if (bid >= cumtb[t + 1]) i = t + 1;
    int rem  = bid - cumtb[i];
    int s    = slen[i];
    int nkt  = s >> 6;
    int head = rem / nkt;
    int t0   = (rem - head * nkt) << 6;

    int tid = threadIdx.x;
    int row = tid >> 2, cg = tid & 3;
    const float* src = b + (long)(toff[i] + t0 + row) * 1024 + head * 64 + cg * 16;
    #pragma unroll
    for (int e4 = 0; e4 < 4; ++e4) {
        f32x4 v = *(const f32x4*)(src + e4 * 4);
        #pragma unroll
        for (int e = 0; e < 4; ++e)
            T[cg * 16 + e4 * 4 + e][row] = (unsigned short)f2b(v[e]);
    }
    __syncthreads();
    int col = tid >> 2, kq = tid & 3;
    int sw  = col & 7;
    unsigned short* base = bt + (long)toff[i] * 1024 + (long)head * 64 * s
                              + (long)col * s + t0;
    *(bf16x8*)(base + (((kq * 2    ) ^ sw) * 8)) = *(const bf16x8*)&T[col][kq * 16];
    *(bf16x8*)(base + (((kq * 2 + 1) ^ sw) * 8)) = *(const bf16x8*)&T[col][kq * 16 + 8];
}

// ---- One pipeline half: compute bufC (tile kk), prefetch kpre into bufP ----
__device__ __forceinline__ void do_half(const float* ar0, const float* ar1, int kk,
                                        const unsigned short* g0, const unsigned short* g1,
                                        int kpre, unsigned short* bufC, unsigned short* bufP,
                                        int wave, int lrow, int lgrp, f32x4 acc[2][4]) {
    __builtin_amdgcn_s_barrier();          // all waves done READING bufP (prev use)
    GLDS(g0 + kpre, bufP + wave * 1024);   // 8 j-rows x 128B, linear
    GLDS(g1 + kpre, bufP + wave * 1024 + 512);
    f32x4 a00 = *(const f32x4*)(ar0 + kk);
    f32x4 a01 = *(const f32x4*)(ar0 + kk + 4);
    f32x4 a02 = *(const f32x4*)(ar0 + kk + 32);
    f32x4 a03 = *(const f32x4*)(ar0 + kk + 36);
    f32x4 a10 = *(const f32x4*)(ar1 + kk);
    f32x4 a11 = *(const f32x4*)(ar1 + kk + 4);
    f32x4 a12 = *(const f32x4*)(ar1 + kk + 32);
    f32x4 a13 = *(const f32x4*)(ar1 + kk + 36);
    // newest 10 vmem = {2 glds(kpre), 8 A}; completing older => bufC's glds done.
    asm volatile("s_waitcnt vmcnt(10)" ::: "memory");
    __builtin_amdgcn_s_barrier();          // bufC staged by ALL waves

    bf16x8 af0 = cvt8(a00, a01), af1 = cvt8(a10, a11);
    bf16x8 bf0[4];
    #pragma unroll
    for (int nt = 0; nt < 4; ++nt) {
        int j = nt * 16 + lrow;
        bf0[nt] = *(const bf16x8*)&bufC[j * 64 + ((lgrp ^ (j & 7)) * 8)];
    }
    #pragma unroll
    for (int nt = 0; nt < 4; ++nt) {
        acc[0][nt] = __builtin_amdgcn_mfma_f32_16x16x32_bf16(af0, bf0[nt], acc[0][nt], 0, 0, 0);
        acc[1][nt] = __builtin_amdgcn_mfma_f32_16x16x32_bf16(af1, bf0[nt], acc[1][nt], 0, 0, 0);
    }
    bf16x8 af2 = cvt8(a02, a03), af3 = cvt8(a12, a13);
    bf16x8 bf1[4];
    #pragma unroll
    for (int nt = 0; nt < 4; ++nt) {
        int j = nt * 16 + lrow;
        bf1[nt] = *(const bf16x8*)&bufC[j * 64 + (((lgrp + 4) ^ (j & 7)) * 8)];
    }
    #pragma unroll
    for (int nt = 0; nt < 4; ++nt) {
        acc[0][nt] = __builtin_amdgcn_mfma_f32_16x16x32_bf16(af2, bf1[nt], acc[0][nt], 0, 0, 0);
        acc[1][nt] = __builtin_amdgcn_mfma_f32_16x16x32_bf16(af3, bf1[nt], acc[1][nt], 0, 0, 0);
    }
}

__global__ __launch_bounds__(256) void bmm2_main(const float* __restrict__ a,
                                                 const unsigned short* __restrict__ bt,
                                                 float* __restrict__ out) {
    const int  cumblk[9] = {0,256,448,608,736,848,944,1024,1088};
    const int  slen[8]   = {2048,1536,1280,1024,896,768,640,512};
    const long aoff[8]   = {20971520,88080384,135266304,4194304,161480704,125829120,174325760,0};
    const int  toff[8]   = {1536,3584,5888,512,7168,5120,8064,0};

    __shared__ unsigned short buf0[64 * 64];
    __shared__ unsigned short buf1[64 * 64];

    int bid = blockIdx.x;
    int i = 0;
    #pragma unroll
    for (int t = 0; t < 7; ++t) if (bid >= cumblk[t + 1]) i = t + 1;
    int rem  = bid - cumblk[i];
    int s    = slen[i];
    int nmb  = s >> 7;
    int head = rem / nmb;
    int mb   = rem - head * nmb;

    const float* A = a + aoff[i] + (long)head * s * s + (long)mb * 128 * s;
    const unsigned short* Bt = bt + (long)toff[i] * 1024 + (long)head * 64 * s;
    float* Cp = out + (long)(toff[i] + mb * 128) * 1024 + head * 64;

    int tid = threadIdx.x, lane = tid & 63, wave = tid >> 6;
    int lrow = lane & 15, lgrp = lane >> 4;

    const float* ar0 = A + (long)(wave * 32 + lrow) * s + lgrp * 8;
    const float* ar1 = ar0 + (long)16 * s;

    // glds source: wave stages j = wave*16 .. +15 (2 instructions). lane l: j += l>>3, chunk = l&7.
    const unsigned short* g0 = Bt + (long)(wave * 16 + (lane >> 3)) * s + (lane & 7) * 8;
    const unsigned short* g1 = g0 + (long)8 * s;

    f32x4 acc[2][4] = {};

    // Prologue: stage k=0 into buf0 (2 glds/wave outstanding entering the loop)
    GLDS(g0, buf0 + wave * 1024);
    GLDS(g1, buf0 + wave * 1024 + 512);

    for (int k0 = 0; k0 < s; k0 += 128) {   // all s are multiples of 128
        int kp2 = (k0 + 128 < s) ? (k0 + 128) : 0;  // last-iter dummy prefetch
        do_half(ar0, ar1, k0,      g0, g1, k0 + 64, buf0, buf1, wave, lrow, lgrp, acc);
        do_half(ar0, ar1, k0 + 64, g0, g1, kp2,     buf1, buf0, wave, lrow, lgrp, acc);
    }

    #pragma unroll
    for (int mt = 0; mt < 2; ++mt)
        #pragma unroll
        for (int nt = 0; nt < 4; ++nt)
            #pragma unroll
            for (int r = 0; r < 4; ++r) {
                int q = wave * 32 + mt * 16 + lgrp * 4 + r;
                Cp[(long)q * 1024 + nt * 16 + lrow] = acc[mt][nt][r];
            }
}

// ---------------- Fallback (round-1 kernel, proven 181us) if ws too small ----------------
#define LDB 40
__device__ inline unsigned pack2(float lo, float hi) {
    return (unsigned)(unsigned short)f2b(lo) | ((unsigned)(unsigned short)f2b(hi) << 16);
}
__global__ __launch_bounds__(256) void bmm2_kernel_lds(const float* __restrict__ a,
                                                       const float* __restrict__ b,
                                                       float* __restrict__ out) {
    const int  cumblk[9] = {0,64,192,448,640,736,896,1008,1088};
    const int  slen[8]   = {512,1024,2048,1536,768,1280,896,640};
    const long aoff[8]   = {0,4194304,20971520,88080384,125829120,135266304,161480704,174325760};
    const int  toff[8]   = {0,512,1536,3584,5120,5888,7168,8064};
    __shared__ unsigned short Bt[64 * LDB];

    int bid = blockIdx.x;
    int i = 0;
    #pragma unroll
    for (int t = 0; t < 7; ++t) if (bid >= cumblk[t + 1]) i = t + 1;
    int rem = bid - cumblk[i];
    int s = slen[i];
    int nmb = s >> 7;
    int head = rem / nmb;
    int mb = rem - head * nmb;

    const float* A  = a + aoff[i] + (long)head * s * s + (long)mb * 128 * s;
    const float* Bp = b + (long)toff[i] * 1024 + head * 64;
    float*       Cp = out + (long)(toff[i] + mb * 128) * 1024 + head * 64;

    int tid = threadIdx.x, lane = tid & 63, wave = tid >> 6;
    int lrow = lane & 15, lgrp = lane >> 4;
    f32x4 acc[2][4] = {};
    int k2 = tid >> 4;
    int j0 = (tid & 15) * 4;
    const float* arow0 = A + (long)(wave * 32 + lrow) * s + lgrp * 8;
    const float* arow1 = arow0 + (long)16 * s;

    for (int k0 = 0; k0 < s; k0 += 32) {
        f32x4 a00 = *(const f32x4*)(arow0 + k0);
        f32x4 a01 = *(const f32x4*)(arow0 + k0 + 4);
        f32x4 a10 = *(const f32x4*)(arow1 + k0);
        f32x4 a11 = *(const f32x4*)(arow1 + k0 + 4);
        const float* bpp = Bp + (long)(k0 + 2 * k2) * 1024 + j0;
        f32x4 b0 = *(const f32x4*)bpp;
        f32x4 b1 = *(const f32x4*)(bpp + 1024);
        __syncthreads();
        #pragma unroll
        for (int e = 0; e < 4; ++e)
            *(unsigned*)&Bt[(j0 + e) * LDB + 2 * k2] = pack2(b0[e], b1[e]);
        __syncthreads();
        bf16x8 bf[4];
        #pragma unroll
        for (int nt = 0; nt < 4; ++nt)
            bf[nt] = *(const bf16x8*)&Bt[(nt * 16 + lrow) * LDB + lgrp * 8];
        bf16x8 af0 = cvt8(a00, a01), af1 = cvt8(a10, a11);
        #pragma unroll
        for (int nt = 0; nt < 4; ++nt) {
            acc[0][nt] = __builtin_amdgcn_mfma_f32_16x16x32_bf16(af0, bf[nt], acc[0][nt], 0, 0, 0);
            acc[1][nt] = __builtin_amdgcn_mfma_f32_16x16x32_bf16(af1, bf[nt], acc[1][nt], 0, 0, 0);
        }
    }
    #pragma unroll
    for (int mt = 0; mt < 2; ++mt)
        #pragma unroll
        for (int nt = 0; nt < 4; ++nt)
            #pragma unroll
            for (int r = 0; r < 4; ++r) {
                int q = wave * 32 + mt * 16 + lgrp * 4 + r;
                Cp[(long)q * 1024 + nt * 16 + lrow] = acc[mt][nt][r];
            }
}

extern "C" void kernel_launch(void* const* d_in, const int* in_sizes, int n_in,
                              void* d_out, int out_size, void* d_ws, size_t ws_size,
                              hipStream_t stream) {
    const float* a = (const float*)d_in[0];
    const float* b = (const float*)d_in[1];
    float* out = (float*)d_out;
    const size_t BT_BYTES = 8704UL * 1024UL * 2UL;  // 17.8 MB bf16 transposed B
    if (ws_size >= BT_BYTES) {
        transposeB<<<2176, 256, 0, stream>>>(b, (unsigned short*)d_ws);
        bmm2_main<<<1088, 256, 0, stream>>>(a, (const unsigned short*)d_ws, out);
    } else {
        bmm2_kernel_lds<<<1088, 256, 0, stream>>>(a, b, out);
    }
}

// Round 5
// 191.619 us; speedup vs baseline: 1.1944x; 1.0481x over previous
//
#include <hip/hip_runtime.h>
#include <hip/hip_bf16.h>

typedef __attribute__((ext_vector_type(4))) float f32x4;
typedef __attribute__((ext_vector_type(8))) short bf16x8;

__device__ __forceinline__ unsigned cvt2(float lo, float hi) {
    float2 t; t.x = lo; t.y = hi;
    __hip_bfloat162 h = __float22bfloat162_rn(t);   // v_cvt_pk_bf16_f32
    union { __hip_bfloat162 h; unsigned u; } c; c.h = h; return c.u;
}
__device__ __forceinline__ bf16x8 cvt8(f32x4 lo, f32x4 hi) {
    union { bf16x8 v; unsigned u[4]; } r;
    r.u[0] = cvt2(lo[0], lo[1]); r.u[1] = cvt2(lo[2], lo[3]);
    r.u[2] = cvt2(hi[0], hi[1]); r.u[3] = cvt2(hi[2], hi[3]);
    return r.v;
}

// M=64 per block, 2 waves, K-step 64, B dbuf in LDS (pad 72 shorts/row), 1 barrier/tile.
__global__ __launch_bounds__(128, 4) void bmm2_k(const float* __restrict__ a,
                                                 const float* __restrict__ b,
                                                 float* __restrict__ out) {
    // Desc-sorted static ragged tables (M=64 blocks: 16*s/64 per seq).
    const int  cumblk[9] = {0,512,896,1216,1472,1696,1888,2048,2176};
    const int  slen[8]   = {2048,1536,1280,1024,896,768,640,512};
    const long aoff[8]   = {20971520,88080384,135266304,4194304,161480704,125829120,174325760,0};
    const int  toff[8]   = {1536,3584,5888,512,7168,5120,8064,0};

    __shared__ unsigned short Bt[2][64 * 72];  // [buf][col j][k] bf16, 9 KB each

    int bid = blockIdx.x;
    int i = 0;
    #pragma unroll
    for (int t = 0; t < 7; ++t) if (bid >= cumblk[t + 1]) i = t + 1;
    int rem  = bid - cumblk[i];
    int s    = slen[i];
    int nmb  = s >> 6;                 // 64-row blocks per head
    int head = rem / nmb;
    int mb   = rem - head * nmb;

    const float* A  = a + aoff[i] + (long)head * s * s + (long)mb * 64 * s;
    const float* Bp = b + (long)toff[i] * 1024 + head * 64;
    float*       Cp = out + (long)(toff[i] + mb * 64) * 1024 + head * 64;

    int tid = threadIdx.x, lane = tid & 63, wave = tid >> 6;   // 2 waves
    int lrow = lane & 15, lgrp = lane >> 4;

    // B staging map: thread covers 8 tokens (kb..kb+7) x 4 cols (j0..j0+3)
    int j0 = (tid & 15) * 4;
    int kb = (tid >> 4) * 8;
    const float* bsrc = Bp + (long)kb * 1024 + j0;

    // A map: wave w owns rows w*32..w*32+31
    const float* ar0 = A + (long)(wave * 32 + lrow) * s + lgrp * 8;
    const float* ar1 = ar0 + (long)16 * s;

    f32x4 acc[2][4] = {};
    int NT = s >> 6;

    // ---- prologue: stage tile 0 into buf 0 ----
    {
        f32x4 r[8];
        #pragma unroll
        for (int q = 0; q < 8; ++q) r[q] = *(const f32x4*)(bsrc + (long)q * 1024);
        #pragma unroll
        for (int e = 0; e < 4; ++e) {
            uint4 w;
            w.x = cvt2(r[0][e], r[1][e]); w.y = cvt2(r[2][e], r[3][e]);
            w.z = cvt2(r[4][e], r[5][e]); w.w = cvt2(r[6][e], r[7][e]);
            *(uint4*)&Bt[0][(j0 + e) * 72 + kb] = w;
        }
    }
    __syncthreads();

    for (int t = 0; t < NT; ++t) {
        int cur = t & 1, nxt = cur ^ 1;
        int k0 = t << 6;
        int kn = (t + 1 < NT) ? (k0 + 64) : 0;  // dummy last prefetch

        // global-load B(t+1) (regs die at ds_write below)
        f32x4 r[8];
        #pragma unroll
        for (int q = 0; q < 8; ++q) r[q] = *(const f32x4*)(bsrc + (long)(kn + q) * 1024);

        __syncthreads();  // the ONE barrier: separates reads(t-1)|writes(t+1) and writes(t)|reads(t)

        #pragma unroll
        for (int e = 0; e < 4; ++e) {
            uint4 w;
            w.x = cvt2(r[0][e], r[1][e]); w.y = cvt2(r[2][e], r[3][e]);
            w.z = cvt2(r[4][e], r[5][e]); w.w = cvt2(r[6][e], r[7][e]);
            *(uint4*)&Bt[nxt][(j0 + e) * 72 + kb] = w;
        }

        // A(t): the 723 MB stream, global->VGPR
        f32x4 a000 = *(const f32x4*)(ar0 + k0);
        f32x4 a001 = *(const f32x4*)(ar0 + k0 + 4);
        f32x4 a010 = *(const f32x4*)(ar0 + k0 + 32);
        f32x4 a011 = *(const f32x4*)(ar0 + k0 + 36);
        f32x4 a100 = *(const f32x4*)(ar1 + k0);
        f32x4 a101 = *(const f32x4*)(ar1 + k0 + 4);
        f32x4 a110 = *(const f32x4*)(ar1 + k0 + 32);
        f32x4 a111 = *(const f32x4*)(ar1 + k0 + 36);

        // compute tile t from Bt[cur]
        {
            bf16x8 af0 = cvt8(a000, a001), af1 = cvt8(a100, a101);
            bf16x8 bf[4];
            #pragma unroll
            for (int n = 0; n < 4; ++n)
                bf[n] = *(const bf16x8*)&Bt[cur][(n * 16 + lrow) * 72 + lgrp * 8];
            #pragma unroll
            for (int n = 0; n < 4; ++n) {
                acc[0][n] = __builtin_amdgcn_mfma_f32_16x16x32_bf16(af0, bf[n], acc[0][n], 0, 0, 0);
                acc[1][n] = __builtin_amdgcn_mfma_f32_16x16x32_bf16(af1, bf[n], acc[1][n], 0, 0, 0);
            }
        }
        {
            bf16x8 af2 = cvt8(a010, a011), af3 = cvt8(a110, a111);
            bf16x8 bf[4];
            #pragma unroll
            for (int n = 0; n < 4; ++n)
                bf[n] = *(const bf16x8*)&Bt[cur][(n * 16 + lrow) * 72 + 32 + lgrp * 8];
            #pragma unroll
            for (int n = 0; n < 4; ++n) {
                acc[0][n] = __builtin_amdgcn_mfma_f32_16x16x32_bf16(af2, bf[n], acc[0][n], 0, 0, 0);
                acc[1][n] = __builtin_amdgcn_mfma_f32_16x16x32_bf16(af3, bf[n], acc[1][n], 0, 0, 0);
            }
        }
    }

    // epilogue: C/D layout col=lane&15, row=4*(lane>>4)+reg (verified R1)
    #pragma unroll
    for (int mt = 0; mt < 2; ++mt)
        #pragma unroll
        for (int n = 0; n < 4; ++n)
            #pragma unroll
            for (int rr = 0; rr < 4; ++rr) {
                int q = wave * 32 + mt * 16 + lgrp * 4 + rr;
                Cp[(long)q * 1024 + n * 16 + lrow] = acc[mt][n][rr];
            }
}

extern "C" void kernel_launch(void* const* d_in, const int* in_sizes, int n_in,
                              void* d_out, int out_size, void* d_ws, size_t ws_size,
                              hipStream_t stream) {
    const float* a = (const float*)d_in[0];
    const float* b = (const float*)d_in[1];
    float* out = (float*)d_out;
    bmm2_k<<<2176, 128, 0, stream>>>(a, b, out);
}

// Round 6
// 178.069 us; speedup vs baseline: 1.2853x; 1.0761x over previous
//
#include <hip/hip_runtime.h>
#include <hip/hip_bf16.h>

typedef __attribute__((ext_vector_type(4))) float f32x4;
typedef __attribute__((ext_vector_type(8))) short bf16x8;
typedef __attribute__((ext_vector_type(4))) short bf16x4;

__device__ __forceinline__ unsigned cvt2(float lo, float hi) {
    float2 t; t.x = lo; t.y = hi;
    __hip_bfloat162 h = __float22bfloat162_rn(t);   // v_cvt_pk_bf16_f32
    union { __hip_bfloat162 h; unsigned u; } c; c.h = h; return c.u;
}

// M=128, K-tile=64, 256 threads (4 waves). A AND B staged in LDS (bf16, pad-72 rows).
// A global reads are 256B-contiguous per row-chunk (4 rows x 256B per wave instr)
// -- the granularity experiment. Loads(t+1) issued at compute(t) start, drained at
// the next tile's first barrier (they fly under compute).
__global__ __launch_bounds__(256, 3) void bmm2_k(const float* __restrict__ a,
                                                 const float* __restrict__ b,
                                                 float* __restrict__ out) {
    // Desc-sorted static ragged tables (M=128: 16*s/128 = s/8 blocks per seq).
    const int  cumblk[9] = {0,256,448,608,736,848,944,1024,1088};
    const int  slen[8]   = {2048,1536,1280,1024,896,768,640,512};
    const long aoff[8]   = {20971520,88080384,135266304,4194304,161480704,125829120,174325760,0};
    const int  toff[8]   = {1536,3584,5888,512,7168,5120,8064,0};

    __shared__ unsigned short As[128 * 72];  // [row][k] bf16, 18 KB
    __shared__ unsigned short Bs[64 * 72];   // [col j][k] bf16, 9 KB

    int bid = blockIdx.x;
    int i = 0;
    #pragma unroll
    for (int t = 0; t < 7; ++t) if (bid >= cumblk[t + 1]) i = t + 1;
    int rem  = bid - cumblk[i];
    int s    = slen[i];
    int nmb  = s >> 7;
    int head = rem / nmb;
    int mb   = rem - head * nmb;

    const float* A  = a + aoff[i] + (long)head * s * s + (long)mb * 128 * s;
    const float* Bp = b + (long)toff[i] * 1024 + head * 64;
    float*       Cp = out + (long)(toff[i] + mb * 128) * 1024 + head * 64;

    int tid = threadIdx.x, lane = tid & 63, wave = tid >> 6;
    int lrow = lane & 15, lgrp = lane >> 4;

    // A staging map: thread -> rows {q*16 + (tid>>4)}, floats kf..kf+3 within the
    // 64-float k-chunk. Wave instr = 4 consecutive rows x 256B contiguous each.
    int arow = tid >> 4;           // 0..15
    int kf   = (tid & 15) * 4;     // 0..60
    const float* Ast = A + (long)arow * s + kf;

    // B staging map: thread -> k-rows bk0..bk0+3, cols bj0..bj0+3 (B is L2/L3-hot)
    int bj0 = (tid & 15) * 4;
    int bk0 = (tid >> 4) * 4;
    const float* Bst = Bp + (long)bk0 * 1024 + bj0;

    f32x4 rA[8], rB[4];
    f32x4 acc[2][4] = {};
    int NT = s >> 6;

    // prologue: load tile 0 into regs
    #pragma unroll
    for (int q = 0; q < 8; ++q) rA[q] = *(const f32x4*)(Ast + (long)(q * 16) * s);
    #pragma unroll
    for (int q = 0; q < 4; ++q) rB[q] = *(const f32x4*)(Bst + (long)q * 1024);

    for (int t = 0; t < NT; ++t) {
        __syncthreads();   // #1: compute(t-1) done reading As/Bs; drains loads(t)

        // stage tile t: cvt_pk + ds_write (single-buffer is safe: writes fenced
        // from reads by barrier #2, reads fenced from next writes by barrier #1)
        #pragma unroll
        for (int q = 0; q < 8; ++q) {
            int r = q * 16 + arow;
            union { bf16x4 v; unsigned u[2]; } w;
            w.u[0] = cvt2(rA[q][0], rA[q][1]);
            w.u[1] = cvt2(rA[q][2], rA[q][3]);
            *(bf16x4*)&As[r * 72 + kf] = w.v;
        }
        #pragma unroll
        for (int e = 0; e < 4; ++e) {
            union { bf16x4 v; unsigned u[2]; } w;
            w.u[0] = cvt2(rB[0][e], rB[1][e]);
            w.u[1] = cvt2(rB[2][e], rB[3][e]);
            *(bf16x4*)&Bs[(bj0 + e) * 72 + bk0] = w.v;
        }

        __syncthreads();   // #2: tile t visible (drains only LDS, no vmem pending)

        // issue loads(t+1) NOW -- they fly under compute(t), drain at next barrier #1
        if (t + 1 < NT) {
            int kn = (t + 1) << 6;
            #pragma unroll
            for (int q = 0; q < 8; ++q) rA[q] = *(const f32x4*)(Ast + (long)(q * 16) * s + kn);
            #pragma unroll
            for (int q = 0; q < 4; ++q) rB[q] = *(const f32x4*)(Bst + (long)(kn + q) * 1024);
        }

        // compute tile t: 16 MFMA / wave
        #pragma unroll
        for (int ks = 0; ks < 2; ++ks) {
            bf16x8 af0 = *(const bf16x8*)&As[(wave * 32 + lrow) * 72 + ks * 32 + lgrp * 8];
            bf16x8 af1 = *(const bf16x8*)&As[(wave * 32 + 16 + lrow) * 72 + ks * 32 + lgrp * 8];
            bf16x8 bf[4];
            #pragma unroll
            for (int n = 0; n < 4; ++n)
                bf[n] = *(const bf16x8*)&Bs[(n * 16 + lrow) * 72 + ks * 32 + lgrp * 8];
            #pragma unroll
            for (int n = 0; n < 4; ++n) {
                acc[0][n] = __builtin_amdgcn_mfma_f32_16x16x32_bf16(af0, bf[n], acc[0][n], 0, 0, 0);
                acc[1][n] = __builtin_amdgcn_mfma_f32_16x16x32_bf16(af1, bf[n], acc[1][n], 0, 0, 0);
            }
        }
    }

    // epilogue: C/D layout col=lane&15, row=4*(lane>>4)+reg (verified R1)
    #pragma unroll
    for (int mt = 0; mt < 2; ++mt)
        #pragma unroll
        for (int n = 0; n < 4; ++n)
            #pragma unroll
            for (int r = 0; r < 4; ++r) {
                int q = wave * 32 + mt * 16 + lgrp * 4 + r;
                Cp[(long)q * 1024 + n * 16 + lrow] = acc[mt][n][r];
            }
}

extern "C" void kernel_launch(void* const* d_in, const int* in_sizes, int n_in,
                              void* d_out, int out_size, void* d_ws, size_t ws_size,
                              hipStream_t stream) {
    const float* a = (const float*)d_in[0];
    const float* b = (const float*)d_in[1];
    float* out = (float*)d_out;
    bmm2_k<<<1088, 256, 0, stream>>>(a, b, out);
}

// Round 7
// 173.263 us; speedup vs baseline: 1.3210x; 1.0277x over previous
//
#include <hip/hip_runtime.h>
#include <hip/hip_bf16.h>

typedef __attribute__((ext_vector_type(4))) float f32x4;
typedef __attribute__((ext_vector_type(8))) short bf16x8;
typedef __attribute__((ext_vector_type(4))) short bf16x4;

__device__ __forceinline__ unsigned cvt2(float lo, float hi) {
    float2 t; t.x = lo; t.y = hi;
    __hip_bfloat162 h = __float22bfloat162_rn(t);   // v_cvt_pk_bf16_f32
    union { __hip_bfloat162 h; unsigned u; } c; c.h = h; return c.u;
}

// M=64, K-step 64, 4 waves. Depth-2 pipeline: raw s_barrier (no vmcnt drain),
// LDS double-buffered, loads(t+2) issued in phase t -> ~2 phase-times of latency
// cover. A loads nontemporal (read-once stream; keep L2 for B).
__global__ __launch_bounds__(256, 4) void bmm2_k(const float* __restrict__ a,
                                                 const float* __restrict__ b,
                                                 float* __restrict__ out) {
    // Desc-sorted static ragged tables (M=64: 16*s/64 = s/4 blocks per seq).
    const int  cumblk[9] = {0,512,896,1216,1472,1696,1888,2048,2176};
    const int  slen[8]   = {2048,1536,1280,1024,896,768,640,512};
    const long aoff[8]   = {20971520,88080384,135266304,4194304,161480704,125829120,174325760,0};
    const int  toff[8]   = {1536,3584,5888,512,7168,5120,8064,0};

    __shared__ unsigned short As[2][64 * 72];  // [buf][row][k] bf16 (+8 pad: 2-way banks max)
    __shared__ unsigned short Bs[2][64 * 72];  // [buf][col j][k] bf16

    int bid = blockIdx.x;
    int i = 0;
    #pragma unroll
    for (int t = 0; t < 7; ++t) if (bid >= cumblk[t + 1]) i = t + 1;
    int rem  = bid - cumblk[i];
    int s    = slen[i];
    int nmb  = s >> 6;
    int head = rem / nmb;
    int mb   = rem - head * nmb;

    const float* A  = a + aoff[i] + (long)head * s * s + (long)mb * 64 * s;
    const float* Bp = b + (long)toff[i] * 1024 + head * 64;
    float*       Cp = out + (long)(toff[i] + mb * 64) * 1024 + head * 64;

    int tid = threadIdx.x, lane = tid & 63, wave = tid >> 6;
    int lrow = lane & 15, lgrp = lane >> 4;

    // A staging: thread -> rows {arow+16q}, 16B chunk kq. Wave instr = 4 rows x 256B contiguous.
    int arow = tid >> 4;          // 0..15
    int kq   = tid & 15;
    const float* Ast = A + (long)arow * s + kq * 4;

    // B staging: thread -> tokens {btok..btok+3} x cols {bcol..bcol+3} (B is L2/L3-hot)
    int bcol = (tid & 15) * 4;
    int btok = (tid >> 4) * 4;
    const float* Bst = Bp + (long)btok * 1024 + bcol;

    f32x4 lA0[4], lB0[4], lA1[4], lB1[4];   // two static register sets (depth-2)
    f32x4 acc[4] = {};

    // prologue: tiles 0 and 1 in flight
    #pragma unroll
    for (int q = 0; q < 4; ++q) {
        lA0[q] = __builtin_nontemporal_load((const f32x4*)(Ast + (long)(16 * q) * s));
        lA1[q] = __builtin_nontemporal_load((const f32x4*)(Ast + (long)(16 * q) * s + 64));
        lB0[q] = *(const f32x4*)(Bst + (long)q * 1024);
        lB1[q] = *(const f32x4*)(Bst + (long)(64 + q) * 1024);
    }

    int NTt = s >> 6;   // always even for these seqlens
    for (int t = 0; t < NTt; t += 2) {
        // ================= even phase: buf0 = tile t, prefetch t+2 =================
        __builtin_amdgcn_s_barrier();              // readers of buf0 (tile t-2) done; NO vmem drain
        #pragma unroll
        for (int q = 0; q < 4; ++q) {              // stage A (compiler waits vmcnt for lA0 only)
            union { bf16x4 v; unsigned u[2]; } w;
            w.u[0] = cvt2(lA0[q][0], lA0[q][1]);
            w.u[1] = cvt2(lA0[q][2], lA0[q][3]);
            *(bf16x4*)&As[0][(arow + 16 * q) * 72 + kq * 4] = w.v;
        }
        #pragma unroll
        for (int e = 0; e < 4; ++e) {              // stage B
            union { bf16x4 v; unsigned u[2]; } w;
            w.u[0] = cvt2(lB0[0][e], lB0[1][e]);
            w.u[1] = cvt2(lB0[2][e], lB0[3][e]);
            *(bf16x4*)&Bs[0][(bcol + e) * 72 + btok] = w.v;
        }
        {
            long kn = (t + 2 < NTt) ? ((long)(t + 2) << 6) : 0;
            #pragma unroll
            for (int q = 0; q < 4; ++q) {
                lA0[q] = __builtin_nontemporal_load((const f32x4*)(Ast + (long)(16 * q) * s + kn));
                lB0[q] = *(const f32x4*)(Bst + (kn + q) * 1024);
            }
        }
        asm volatile("s_waitcnt lgkmcnt(0)" ::: "memory");
        __builtin_amdgcn_sched_barrier(0);
        __builtin_amdgcn_s_barrier();              // buf0 visible
        #pragma unroll
        for (int ks = 0; ks < 2; ++ks) {
            bf16x8 af = *(const bf16x8*)&As[0][(wave * 16 + lrow) * 72 + ks * 32 + lgrp * 8];
            #pragma unroll
            for (int n = 0; n < 4; ++n) {
                bf16x8 bf = *(const bf16x8*)&Bs[0][(n * 16 + lrow) * 72 + ks * 32 + lgrp * 8];
                acc[n] = __builtin_amdgcn_mfma_f32_16x16x32_bf16(af, bf, acc[n], 0, 0, 0);
            }
        }
        // ================= odd phase: buf1 = tile t+1, prefetch t+3 =================
        __builtin_amdgcn_s_barrier();
        #pragma unroll
        for (int q = 0; q < 4; ++q) {
            union { bf16x4 v; unsigned u[2]; } w;
            w.u[0] = cvt2(lA1[q][0], lA1[q][1]);
            w.u[1] = cvt2(lA1[q][2], lA1[q][3]);
            *(bf16x4*)&As[1][(arow + 16 * q) * 72 + kq * 4] = w.v;
        }
        #pragma unroll
        for (int e = 0; e < 4; ++e) {
            union { bf16x4 v; unsigned u[2]; } w;
            w.u[0] = cvt2(lB1[0][e], lB1[1][e]);
            w.u[1] = cvt2(lB1[2][e], lB1[3][e]);
            *(bf16x4*)&Bs[1][(bcol + e) * 72 + btok] = w.v;
        }
        {
            long kn = (t + 3 < NTt) ? ((long)(t + 3) << 6) : 0;
            #pragma unroll
            for (int q = 0; q < 4; ++q) {
                lA1[q] = __builtin_nontemporal_load((const f32x4*)(Ast + (long)(16 * q) * s + kn));
                lB1[q] = *(const f32x4*)(Bst + (kn + q) * 1024);
            }
        }
        asm volatile("s_waitcnt lgkmcnt(0)" ::: "memory");
        __builtin_amdgcn_sched_barrier(0);
        __builtin_amdgcn_s_barrier();
        #pragma unroll
        for (int ks = 0; ks < 2; ++ks) {
            bf16x8 af = *(const bf16x8*)&As[1][(wave * 16 + lrow) * 72 + ks * 32 + lgrp * 8];
            #pragma unroll
            for (int n = 0; n < 4; ++n) {
                bf16x8 bf = *(const bf16x8*)&Bs[1][(n * 16 + lrow) * 72 + ks * 32 + lgrp * 8];
                acc[n] = __builtin_amdgcn_mfma_f32_16x16x32_bf16(af, bf, acc[n], 0, 0, 0);
            }
        }
    }

    // epilogue: C/D layout col=lane&15, row=4*(lane>>4)+reg (verified R1); NT stores
    #pragma unroll
    for (int n = 0; n < 4; ++n)
        #pragma unroll
        for (int r = 0; r < 4; ++r) {
            int q = wave * 16 + lgrp * 4 + r;
            __builtin_nontemporal_store(acc[n][r], &Cp[(long)q * 1024 + n * 16 + lrow]);
        }
}

extern "C" void kernel_launch(void* const* d_in, const int* in_sizes, int n_in,
                              void* d_out, int out_size, void* d_ws, size_t ws_size,
                              hipStream_t stream) {
    const float* a = (const float*)d_in[0];
    const float* b = (const float*)d_in[1];
    float* out = (float*)d_out;
    bmm2_k<<<2176, 256, 0, stream>>>(a, b, out);
}